// Round 6
// baseline (317.173 us; speedup 1.0000x reference)
//
#include <hip/hip_runtime.h>
#include <math.h>

// KGAT attention aggregation, MI355X.
// fc1->fc2 with no activation collapses to one linear functional; the ent-dot
// and bias are k-invariant and cancel in the softmax, so
//   logit_k = dot(ne_k, wne) + dot(nr_k, wnr),  w = W1@W2 (cols 128..384).
// R6: software-pipelined grid-stride main loop — each half-wave (32 lanes)
// processes ITER=4 rows, prefetching row i+1's 11 float4 loads into a second
// register buffer while reducing/storing row i. Goal: keep vmem requests
// continuously in flight (Little's law) instead of burst-and-drain per block.

#define DIM 128
#define KN 5
#define ITER 4

typedef float nfloat4 __attribute__((ext_vector_type(4)));

__device__ __forceinline__ float dot4(nfloat4 a, nfloat4 b) {
    return a.x * b.x + a.y * b.y + a.z * b.z + a.w * b.w;
}

template <int CTRL>
__device__ __forceinline__ float dpp_add(float v) {
    int x = __builtin_amdgcn_update_dpp(0, __float_as_int(v), CTRL, 0xF, 0xF, true);
    return v + __int_as_float(x);
}

// Sum across a 32-lane half-wave; result in every lane of the half.
__device__ __forceinline__ float half_reduce(float v) {
    v = dpp_add<0xB1>(v);   // quad_perm xor1
    v = dpp_add<0x4E>(v);   // quad_perm xor2
    v = dpp_add<0x124>(v);  // row_ror:4
    v = dpp_add<0x128>(v);  // row_ror:8 -> 16-lane row sum
    v += __int_as_float(__builtin_amdgcn_ds_swizzle(__float_as_int(v), 0x401F)); // xor16
    return v;
}

// w[t] = sum_a W1[128+t, a] * W2[a] for t in [0,256): [wne | wnr].
__global__ __launch_bounds__(256) void kgat_prep(
    const float* __restrict__ W1,   // [384,128]
    const float* __restrict__ W2,   // [128]
    float* __restrict__ ws)         // w[256]
{
    const int t = blockIdx.x * 4 + (threadIdx.x >> 6);
    const int lane = threadIdx.x & 63;
    if (t < 2 * DIM) {
        const float2 w1 = *(const float2*)(W1 + (size_t)(DIM + t) * DIM + 2 * lane);
        const float2 w2 = *(const float2*)(W2 + 2 * lane);
        float v = w1.x * w2.x + w1.y * w2.y;
        #pragma unroll
        for (int off = 32; off >= 1; off >>= 1) v += __shfl_xor(v, off, 64);
        if (lane == 0) ws[t] = v;
    }
}

// 32 lanes per row; each half-wave walks ITER rows with stride 2*nwaves,
// halves of a wave stay on adjacent rows (p, p+1) for locality.
__global__ __launch_bounds__(256) void kgat_main(
    const float* __restrict__ ent,   // [P, 128]
    const float* __restrict__ ne,    // [P, 5, 128]
    const float* __restrict__ nr,    // [P, 5, 128]
    const float* __restrict__ ws,    // wne[128], wnr[128]
    float* __restrict__ out,         // [P, 256]
    int P)
{
    const int wave = threadIdx.x >> 6;
    const int lane = threadIdx.x & 63;
    const int half = lane >> 5;
    const int l    = lane & 31;
    const int nwaves = gridDim.x * 4;
    const int gw = blockIdx.x * 4 + wave;
    const int d = l * 4;

    const nfloat4 wne = *(const nfloat4*)(ws + d);
    const nfloat4 wnr = *(const nfloat4*)(ws + DIM + d);

    nfloat4 e4[2];
    nfloat4 ne4[2][KN], nr4[2][KN];

    int p = gw * 2 + half;
    const int stride = nwaves * 2;

    // preload iteration 0 into buffer 0
    if (p < P) {
        e4[0] = *(const nfloat4*)(ent + (size_t)p * DIM + d);
        const size_t rowK = ((size_t)p * KN) * DIM + d;
        #pragma unroll
        for (int k = 0; k < KN; ++k) {
            ne4[0][k] = *(const nfloat4*)(ne + rowK + (size_t)k * DIM);
            nr4[0][k] = *(const nfloat4*)(nr + rowK + (size_t)k * DIM);
        }
    }

    #pragma unroll
    for (int i = 0; i < ITER; ++i) {
        const int cur = i & 1;
        const int nxt = cur ^ 1;
        const int pn = p + stride;

        // prefetch next row's data (stays in flight during compute below)
        if (i + 1 < ITER && pn < P) {
            e4[nxt] = *(const nfloat4*)(ent + (size_t)pn * DIM + d);
            const size_t rowKn = ((size_t)pn * KN) * DIM + d;
            #pragma unroll
            for (int k = 0; k < KN; ++k) {
                ne4[nxt][k] = *(const nfloat4*)(ne + rowKn + (size_t)k * DIM);
                nr4[nxt][k] = *(const nfloat4*)(nr + rowKn + (size_t)k * DIM);
            }
        }

        if (p < P) {
            float logit[KN];
            #pragma unroll
            for (int k = 0; k < KN; ++k)
                logit[k] = half_reduce(dot4(ne4[cur][k], wne) + dot4(nr4[cur][k], wnr));

            float m = -INFINITY;
            #pragma unroll
            for (int k = 0; k < KN; ++k) m = fmaxf(m, logit[k]);
            float ex[KN], s = 0.f;
            #pragma unroll
            for (int k = 0; k < KN; ++k) { ex[k] = __expf(logit[k] - m); s += ex[k]; }
            const float inv = 1.f / s;

            nfloat4 acc = {0.f, 0.f, 0.f, 0.f};
            #pragma unroll
            for (int k = 0; k < KN; ++k) {
                const float a = ex[k] * inv;
                acc.x += a * ne4[cur][k].x;
                acc.y += a * ne4[cur][k].y;
                acc.z += a * ne4[cur][k].z;
                acc.w += a * ne4[cur][k].w;
            }

            float* orow = out + (size_t)p * (2 * DIM);
            __builtin_nontemporal_store(e4[cur], (nfloat4*)(orow + d));
            __builtin_nontemporal_store(acc,     (nfloat4*)(orow + DIM + d));
        }
        p = pn;
    }
}

extern "C" void kernel_launch(void* const* d_in, const int* in_sizes, int n_in,
                              void* d_out, int out_size, void* d_ws, size_t ws_size,
                              hipStream_t stream) {
    const float* ent = (const float*)d_in[0];
    const float* ne  = (const float*)d_in[1];
    const float* nr  = (const float*)d_in[2];
    const float* W1  = (const float*)d_in[3];
    const float* W2  = (const float*)d_in[5];
    float* out = (float*)d_out;
    float* ws  = (float*)d_ws;

    const int P = in_sizes[0] / DIM;  // B*N rows

    kgat_prep<<<(2 * DIM + 3) / 4, 256, 0, stream>>>(W1, W2, ws);
    // 8 rows per block-iteration (4 waves x 2 halves), ITER iterations each
    const int blocks = (P + 8 * ITER - 1) / (8 * ITER);
    kgat_main<<<blocks, 256, 0, stream>>>(ent, ne, nr, ws, out, P);
}